// Round 8
// baseline (462.128 us; speedup 1.0000x reference)
//
#include <hip/hip_runtime.h>
#include <stdint.h>

typedef __attribute__((ext_vector_type(8))) short bf16x8;   // 8 bf16 in 4 VGPRs
typedef __attribute__((ext_vector_type(4))) float f32x4;

#define LOG2E 1.44269504088896f
#define T_SEQ 2048

__device__ __forceinline__ float bf2f(short s) {
    unsigned u = ((unsigned)(unsigned short)s) << 16;
    float f; __builtin_memcpy(&f, &u, 4); return f;
}
__device__ __forceinline__ short f2bf(float f) {
    unsigned u; __builtin_memcpy(&u, &f, 4);
    u = (u + 0x7FFFu + ((u >> 16) & 1u)) >> 16;   // RNE
    return (short)u;
}
__device__ __forceinline__ short f2bf_trunc(float f) {
    unsigned u; __builtin_memcpy(&u, &f, 4);
    return (short)(u >> 16);                      // truncate (bias cancels in P/l ratio)
}

#define GLDS(g, l) __builtin_amdgcn_global_load_lds( \
    (const __attribute__((address_space(1))) void*)(g), \
    (__attribute__((address_space(3))) void*)(l), 16, 0, 0)

// ---------------------------------------------------------------------------
// fp32-vs-bf16 input detection. flag[0]=1 if fp32.
__global__ void detect_k(const unsigned short* __restrict__ x, int* __restrict__ flag) {
    int lane = threadIdx.x;            // 64 threads
    int cnt = 0;
    for (int i = lane; i < 2048; i += 64) {
        int e = (x[i] >> 7) & 0xFF;
        if (e >= 0xC0) cnt++;
    }
    cnt += __shfl_xor(cnt, 1);
    cnt += __shfl_xor(cnt, 2);
    cnt += __shfl_xor(cnt, 4);
    cnt += __shfl_xor(cnt, 8);
    cnt += __shfl_xor(cnt, 16);
    cnt += __shfl_xor(cnt, 32);
    if (lane == 0) { flag[0] = (cnt >= 32) ? 1 : 0; flag[1] = 0; }
}

// ---------------------------------------------------------------------------
// merged x-conversion (blocks 0..4095) + 4 bias vectors (blocks 4096..4098:
// [bq:2048 | bk:512 | bv:512 | bo:2048])
__global__ __launch_bounds__(256) void convert_all_k(
    const void* __restrict__ x, short* __restrict__ xb,
    const void* __restrict__ b0, const void* __restrict__ b1,
    const void* __restrict__ b2, const void* __restrict__ b3,
    short* __restrict__ o0, short* __restrict__ o1,
    short* __restrict__ o2, short* __restrict__ o3,
    const int* __restrict__ flag)
{
    const int blk = blockIdx.x;
    const int fp32 = *flag;
    if (blk < 4096) {
        int i = (blk * 256 + threadIdx.x) * 8;
        bf16x8 v;
        if (fp32) {
            const float* f = (const float*)x + i;
            #pragma unroll
            for (int j = 0; j < 8; ++j) v[j] = f2bf(f[j]);
        } else {
            v = *(const bf16x8*)((const short*)x + i);
        }
        *(bf16x8*)(xb + i) = v;
        return;
    }
    int i = ((blk - 4096) * 256 + threadIdx.x) * 8;
    const void* in; short* out; int off;
    if      (i < 2048) { in = b0; out = o0; off = i; }
    else if (i < 2560) { in = b1; out = o1; off = i - 2048; }
    else if (i < 3072) { in = b2; out = o2; off = i - 2560; }
    else if (i < 5120) { in = b3; out = o3; off = i - 3072; }
    else return;
    bf16x8 v;
    if (fp32) {
        const float* f = (const float*)in + off;
        #pragma unroll
        for (int j = 0; j < 8; ++j) v[j] = f2bf(f[j]);
    } else {
        v = *(const bf16x8*)((const short*)in + off);
    }
    *(bf16x8*)(out + off) = v;
}

// ---------------------------------------------------------------------------
// out[c*R + r] = in[r*ldi + c]   (batched via blockIdx.z), input fp32 or bf16
// per flag, output bf16. grid: (C/256, R/64, batch), block 256.
__global__ __launch_bounds__(256) void transpose_k(
    const void* __restrict__ in_, short* __restrict__ out,
    int R, int ldi, long ibstride, long obstride, const int* __restrict__ flag)
{
    short* ob = out + (long)blockIdx.z * obstride;
    int c = blockIdx.x * 256 + threadIdx.x;
    int r0 = blockIdx.y * 64;
    int fp32 = *flag;
    if (fp32) {
        const float* ib = (const float*)in_ + (long)blockIdx.z * ibstride;
        for (int rr = 0; rr < 64; rr += 8) {
            bf16x8 v;
            #pragma unroll
            for (int j = 0; j < 8; ++j) v[j] = f2bf(ib[(long)(r0 + rr + j) * ldi + c]);
            *(bf16x8*)(ob + (long)c * R + r0 + rr) = v;
        }
    } else {
        const short* ib = (const short*)in_ + (long)blockIdx.z * ibstride;
        for (int rr = 0; rr < 64; rr += 8) {
            bf16x8 v;
            #pragma unroll
            for (int j = 0; j < 8; ++j) v[j] = ib[(long)(r0 + rr + j) * ldi + c];
            *(bf16x8*)(ob + (long)c * R + r0 + rr) = v;
        }
    }
}

// ---------------------------------------------------------------------------
// all 4 weight transposes in ONE launch. grid (20, 32):
//  bx 0-7: Wq->Wq_t | 8-9: Wk->Wkv_t | 10-11: Wv->Wkv_t+512*2048 | 12-19: Wo->Wo_t
// All are 2048-row inputs (R=2048).
__global__ __launch_bounds__(256) void transpose4_k(
    const void* __restrict__ Wq, const void* __restrict__ Wk,
    const void* __restrict__ Wv, const void* __restrict__ Wo,
    short* __restrict__ Wq_t, short* __restrict__ Wkv_t,
    short* __restrict__ Wo_t, const int* __restrict__ flag)
{
    const int bx = blockIdx.x;
    const void* in; short* out; int ldi, c;
    if (bx < 8)       { in = Wq; out = Wq_t;                     ldi = 2048; c = bx * 256 + threadIdx.x; }
    else if (bx < 10) { in = Wk; out = Wkv_t;                    ldi = 512;  c = (bx - 8) * 256 + threadIdx.x; }
    else if (bx < 12) { in = Wv; out = Wkv_t + (long)512 * 2048; ldi = 512;  c = (bx - 10) * 256 + threadIdx.x; }
    else              { in = Wo; out = Wo_t;                     ldi = 2048; c = (bx - 12) * 256 + threadIdx.x; }
    const int r0 = blockIdx.y * 64;
    const int fp32 = *flag;
    if (fp32) {
        const float* ib = (const float*)in;
        for (int rr = 0; rr < 64; rr += 8) {
            bf16x8 v;
            #pragma unroll
            for (int j = 0; j < 8; ++j) v[j] = f2bf(ib[(long)(r0 + rr + j) * ldi + c]);
            *(bf16x8*)(out + (long)c * 2048 + r0 + rr) = v;
        }
    } else {
        const short* ib = (const short*)in;
        for (int rr = 0; rr < 64; rr += 8) {
            bf16x8 v;
            #pragma unroll
            for (int j = 0; j < 8; ++j) v[j] = ib[(long)(r0 + rr + j) * ldi + c];
            *(bf16x8*)(out + (long)c * 2048 + r0 + rr) = v;
        }
    }
}

// ---------------------------------------------------------------------------
// gemm_bt<BN> (m97 structure): C = A[M,K] @ Bt[N,K]^T + bias. 128xBN tile,
// BK=32, 4 waves, global_load_lds w=16, XOR chunk swizzle, zero conflicts,
// XCD-aware bijective block swizzle (r6, FETCH 78->60MB).
// r8 FIX: A-staging group-1 row is DERIVED from its chunk index c1=256+tid:
// row = c1>>2 = 64+(tid>>2). (r7 hand-wrote 128+(tid>>2) -> half the A-tile
// unstaged -> absmax 3.46.)
// BN templated {128,96,64}: occupancy was grid-limited (3 blocks/CU at 768);
// BN=96 QKV / BN=64 proj -> 1024 blocks = 4/CU.  nbx = blocks along N.
#define BK 32
template <int BN>
__global__ __launch_bounds__(256) void gemm_bt(
    const short* __restrict__ A, const short* __restrict__ Bt,
    const short* __restrict__ bias1, int nsplit,
    short* __restrict__ C, short* __restrict__ C2, int n2,
    float* __restrict__ Cf, const int* __restrict__ flag,
    int M, int N, int K, int nbx)
{
    constexpr int NT = BN / 32;                 // n-tiles per wave
    __shared__ short a_lds[128 * BK];
    __shared__ short b_lds[BN * BK];
    const int tid = threadIdx.x;
    const int wave = tid >> 6, lane = tid & 63;
    const int quad = lane >> 4, l16 = lane & 15;

    // XCD-aware bijective swizzle: XCD (bid%8) gets contiguous chunk of work
    const int nwg = gridDim.x;
    const int swz = (blockIdx.x & 7) * (nwg >> 3) + (blockIdx.x >> 3);
    const int by = swz / nbx;
    const int bx = swz - by * nbx;
    const int m0 = by * 128, n0 = bx * BN;
    const int wm = (wave >> 1) * 64, wn = (wave & 1) * (BN / 2);

    // staging: chunk index c -> row c>>2, swizzled k-chunk (c&3)^((row>>1)&3).
    // A: chunks c0=tid (rows 0..63), c1=256+tid (rows 64..127).
    // B: chunks c0 (rows 0..63); rows 64..BN-1 via c1 on first (BN-64)*4 thr.
    const int c0i = tid, c1i = 256 + tid;
    const int rA0 = c0i >> 2, kc0 = (c0i & 3) ^ ((rA0 >> 1) & 3);
    const int rA1 = c1i >> 2, kc1 = (c1i & 3) ^ ((rA1 >> 1) & 3);
    const long aoff0 = (long)(m0 + rA0) * K + kc0 * 8;
    const long aoff1 = (long)(m0 + rA1) * K + kc1 * 8;
    const long boff0 = (long)(n0 + rA0) * K + kc0 * 8;
    const long boff1 = (long)(n0 + rA1) * K + kc1 * 8;
    short* alp0 = a_lds + (wave * 64) * 8;          // HW adds lane*16B
    short* alp1 = a_lds + (256 + wave * 64) * 8;
    short* blp0 = b_lds + (wave * 64) * 8;
    short* blp1 = b_lds + (256 + wave * 64) * 8;

    int aro[4], bro[NT];
    #pragma unroll
    for (int t = 0; t < 4; ++t) {
        int ra = wm + t * 16 + l16;
        aro[t] = ra * BK + (quad ^ ((ra >> 1) & 3)) * 8;
    }
    #pragma unroll
    for (int t = 0; t < NT; ++t) {
        int rb = wn + t * 16 + l16;
        bro[t] = rb * BK + (quad ^ ((rb >> 1) & 3)) * 8;
    }

    f32x4 acc[4][NT];
    #pragma unroll
    for (int i = 0; i < 4; ++i)
        #pragma unroll
        for (int j = 0; j < NT; ++j)
            acc[i][j] = (f32x4){0.f, 0.f, 0.f, 0.f};

    for (int k0 = 0; k0 < K; k0 += BK) {
        __syncthreads();
        GLDS(A + aoff0 + k0, alp0);
        GLDS(A + aoff1 + k0, alp1);
        GLDS(Bt + boff0 + k0, blp0);
        if constexpr (BN == 128) {
            GLDS(Bt + boff1 + k0, blp1);
        } else if constexpr (BN == 96) {
            if (wave < 2) GLDS(Bt + boff1 + k0, blp1);
        }
        __syncthreads();
        bf16x8 af[4], bfr[NT];
        #pragma unroll
        for (int t = 0; t < 4; ++t) af[t] = *(const bf16x8*)(a_lds + aro[t]);
        #pragma unroll
        for (int t = 0; t < NT; ++t) bfr[t] = *(const bf16x8*)(b_lds + bro[t]);
        #pragma unroll
        for (int mt = 0; mt < 4; ++mt)
            #pragma unroll
            for (int nt = 0; nt < NT; ++nt)
                acc[mt][nt] = __builtin_amdgcn_mfma_f32_16x16x32_bf16(
                    af[mt], bfr[nt], acc[mt][nt], 0, 0, 0);
    }

    const int f32o = Cf ? *flag : 0;
    #pragma unroll
    for (int nt = 0; nt < NT; ++nt) {
        int col = n0 + wn + nt * 16 + l16;
        float bb = bf2f(bias1[col < nsplit ? col : 0]);
        #pragma unroll
        for (int mt = 0; mt < 4; ++mt)
            #pragma unroll
            for (int r = 0; r < 4; ++r) {
                int row = m0 + wm + mt * 16 + quad * 4 + r;
                float val = acc[mt][nt][r] + bb;
                if (f32o) {
                    Cf[(long)row * N + col] = val;
                } else if (C2) {
                    if (col < n2) C[(long)row * n2 + col] = f2bf(val);
                    else          C2[(long)row * (N - n2) + (col - n2)] = f2bf(val);
                } else {
                    C[(long)row * N + col] = f2bf(val);
                }
            }
    }
}

// ---------------------------------------------------------------------------
// Flash attention v7: NO split-KV, NO atomics. One block per (q-tile, bh) =
// 1024 blocks; each block walks all its keys (2..32 steps of 64), keeps O,l
// in registers, normalizes locally and writes bf16 Attn directly.
// Balance: QTMAP partitions qt into residue classes {w,w+4,w+8,w+12} each
// summing to 34 steps -> every CU ~68 steps. LDS 34816B, launch_bounds(256,4)
// -> 4 blocks/CU, grid fully resident.
#define PLD 68
__global__ __launch_bounds__(256, 4) void attn_k(
    const short* __restrict__ Qf, const short* __restrict__ KVf,
    const short* __restrict__ Vt, short* __restrict__ Attn)
{
    __shared__ short k_lds[64 * PLD];
    __shared__ short vt_lds[64 * PLD];
    __shared__ short p_lds[4 * 32 * PLD];
    const int tid = threadIdx.x;
    const int wave = tid >> 6, lane = tid & 63;
    const int quad = lane >> 4, l16 = lane & 15;

    // id -> (qt, bh). QTMAP: balanced residue-class partition (see header).
    const int id = blockIdx.x;
    const int bh = id & 63;
    const int w = id >> 6;                    // 0..15
    const int QTMAP[16] = {15,13,11,9, 0,2,4,6, 14,12,10,8, 1,3,5,7};
    const int qt = QTMAP[w];
    const int b = bh >> 5, h = bh & 31, hkv = h >> 2;
    const int q0 = qt * 128;
    const int nsteps = 2 * (qt + 1);          // keys [0, (qt+1)*128), 64/step

    // Q A-frags (2 m-tiles), fold exact 1/8 scale
    bf16x8 aq[2][2];
    #pragma unroll
    for (int mt = 0; mt < 2; ++mt) {
        const short* qp = Qf + ((long)(b * T_SEQ + q0 + wave * 32 + mt * 16 + l16) * 2048
                                + h * 64 + quad * 8);
        aq[mt][0] = *(const bf16x8*)qp;
        aq[mt][1] = *(const bf16x8*)(qp + 32);
        #pragma unroll
        for (int j = 0; j < 8; ++j) {
            aq[mt][0][j] = f2bf(bf2f(aq[mt][0][j]) * 0.125f);
            aq[mt][1][j] = f2bf(bf2f(aq[mt][1][j]) * 0.125f);
        }
    }

    // ones B-frag: B[n=l16][k]=1 iff n==0  -> MFMA computes row-sums of P
    bf16x8 onesf;
    {
        short o = (l16 == 0) ? (short)0x3F80 : (short)0;
        #pragma unroll
        for (int j = 0; j < 8; ++j) onesf[j] = o;
    }

    f32x4 o_acc[2][4];
    f32x4 l_acc[2];
    #pragma unroll
    for (int mt = 0; mt < 2; ++mt) {
        l_acc[mt] = (f32x4){0.f, 0.f, 0.f, 0.f};
        #pragma unroll
        for (int dt = 0; dt < 4; ++dt) o_acc[mt][dt] = (f32x4){0.f, 0.f, 0.f, 0.f};
    }

    // staging map: 512 16B-chunks per 64x64 tile, 2 per thread
    const int cA = tid, cB = 256 + tid;
    const int tA = cA >> 3, chA = cA & 7;
    const int tB = cB >> 3, chB = cB & 7;
    const short* kgA = KVf + ((long)(b * T_SEQ + tA) * 1024 + hkv * 64 + chA * 8);
    const short* kgB = KVf + ((long)(b * T_SEQ + tB) * 1024 + hkv * 64 + chB * 8);
    const short* vgA = Vt + ((long)((b * 8 + hkv) * 64 + tA) * 2048 + chA * 8);
    const short* vgB = Vt + ((long)((b * 8 + hkv) * 64 + tB) * 2048 + chB * 8);

    const int rowq0 = q0 + wave * 32 + quad * 4;     // mt adds 16
    short* pw = p_lds + (wave * 32 + quad * 4) * PLD + l16;
    const short* pr = p_lds + (wave * 32 + l16) * PLD + quad * 8;

    // prefetch step 0
    bf16x8 kA = *(const bf16x8*)(kgA);
    bf16x8 kB = *(const bf16x8*)(kgB);
    bf16x8 vA = *(const bf16x8*)(vgA);
    bf16x8 vB = *(const bf16x8*)(vgB);

    for (int s = 0; s < nsteps; ++s) {
        const int kt0 = s * 64;
        const int ktn = ((s + 1 < nsteps) ? (s + 1) : s) * 64;
        __syncthreads();   // prior step's frag reads done
        *(bf16x8*)(k_lds + tA * PLD + chA * 8) = kA;
        *(bf16x8*)(k_lds + tB * PLD + chB * 8) = kB;
        *(bf16x8*)(vt_lds + tA * PLD + chA * 8) = vA;
        *(bf16x8*)(vt_lds + tB * PLD + chB * 8) = vB;
        // issue next step's loads: full step of compute covers the latency
        kA = *(const bf16x8*)(kgA + (long)ktn * 1024);
        kB = *(const bf16x8*)(kgB + (long)ktn * 1024);
        vA = *(const bf16x8*)(vgA + ktn);
        vB = *(const bf16x8*)(vgB + ktn);
        __syncthreads();   // staging visible

        const int masked = (kt0 >= q0);
        // QK streamed per nt: S-tile -> exp -> P store
        #pragma unroll
        for (int nt = 0; nt < 4; ++nt) {
            bf16x8 bk0 = *(const bf16x8*)(k_lds + (nt * 16 + l16) * PLD + quad * 8);
            bf16x8 bk1 = *(const bf16x8*)(k_lds + (nt * 16 + l16) * PLD + 32 + quad * 8);
            #pragma unroll
            for (int mt = 0; mt < 2; ++mt) {
                f32x4 z = (f32x4){0.f, 0.f, 0.f, 0.f};
                z = __builtin_amdgcn_mfma_f32_16x16x32_bf16(aq[mt][0], bk0, z, 0, 0, 0);
                z = __builtin_amdgcn_mfma_f32_16x16x32_bf16(aq[mt][1], bk1, z, 0, 0, 0);
                if (!masked) {
                    #pragma unroll
                    for (int r = 0; r < 4; ++r)
                        z[r] = exp2f(fmaf(z[r], LOG2E, -16.0f));
                } else {
                    const int rowq = rowq0 + mt * 16;
                    const int tcol = kt0 + nt * 16 + l16;
                    #pragma unroll
                    for (int r = 0; r < 4; ++r) {
                        float e = exp2f(fmaf(z[r], LOG2E, -16.0f));
                        z[r] = (tcol <= rowq + r) ? e : 0.0f;
                    }
                }
                #pragma unroll
                for (int r = 0; r < 4; ++r)
                    pw[mt * 16 * PLD + r * PLD + nt * 16] = f2bf_trunc(z[r]);
            }
        }

        // PV: cache ap frags, dt-outer (bv read once per dt)
        bf16x8 ap[2][2];
        #pragma unroll
        for (int mt = 0; mt < 2; ++mt) {
            ap[mt][0] = *(const bf16x8*)(pr + mt * 16 * PLD);
            ap[mt][1] = *(const bf16x8*)(pr + mt * 16 * PLD + 32);
        }
        #pragma unroll
        for (int dt = 0; dt < 4; ++dt) {
            bf16x8 bv0 = *(const bf16x8*)(vt_lds + (dt * 16 + l16) * PLD + quad * 8);
            bf16x8 bv1 = *(const bf16x8*)(vt_lds + (dt * 16 + l16) * PLD + 32 + quad * 8);
            #pragma unroll
            for (int mt = 0; mt < 2; ++mt) {
                o_acc[mt][dt] = __builtin_amdgcn_mfma_f32_16x16x32_bf16(ap[mt][0], bv0, o_acc[mt][dt], 0, 0, 0);
                o_acc[mt][dt] = __builtin_amdgcn_mfma_f32_16x16x32_bf16(ap[mt][1], bv1, o_acc[mt][dt], 0, 0, 0);
            }
        }
        #pragma unroll
        for (int mt = 0; mt < 2; ++mt) {
            l_acc[mt] = __builtin_amdgcn_mfma_f32_16x16x32_bf16(ap[mt][0], onesf, l_acc[mt], 0, 0, 0);
            l_acc[mt] = __builtin_amdgcn_mfma_f32_16x16x32_bf16(ap[mt][1], onesf, l_acc[mt], 0, 0, 0);
        }
    }

    // epilogue: broadcast row-sum l (lives in lane quad*16, col 0), divide,
    // write bf16 Attn directly. Per row, dt loop covers 64 contiguous shorts.
    #pragma unroll
    for (int mt = 0; mt < 2; ++mt)
        #pragma unroll
        for (int r = 0; r < 4; ++r) {
            const float linv = 1.0f / __shfl(l_acc[mt][r], quad << 4);
            const int rowo = q0 + wave * 32 + mt * 16 + quad * 4 + r;
            short* ap = Attn + (long)(b * T_SEQ + rowo) * 2048 + h * 64 + l16;
            #pragma unroll
            for (int dt = 0; dt < 4; ++dt)
                ap[dt * 16] = f2bf(o_acc[mt][dt][r] * linv);
        }
}

// ---------------------------------------------------------------------------
extern "C" void kernel_launch(void* const* d_in, const int* in_sizes, int n_in,
                              void* d_out, int out_size, void* d_ws, size_t ws_size,
                              hipStream_t stream) {
    const void* x  = d_in[0];
    // d_in[1] = causal mask: applied analytically, unused
    const void* Wq = d_in[2];
    const void* bq = d_in[3];
    const void* Wk = d_in[4];
    const void* bk = d_in[5];
    const void* Wv = d_in[6];
    const void* bv = d_in[7];
    const void* Wo = d_in[8];
    const void* bo = d_in[9];

    short* ws    = (short*)d_ws;
    int*   flags = (int*)ws;                          // flags[0]=fp32?, flags[1]=0
    short* base  = ws + 16;
    short* xb    = base;                              // 4096*2048 = 8,388,608 sh
    short* Wq_t  = xb + (long)8388608;                // 2048*2048 = 4,194,304 sh
    short* Wkv_t = Wq_t + (long)4194304;              // 1024*2048 = 2,097,152 sh
    short* regB  = base + (long)17039360;             // past region A
    short* bqb   = regB;                              // 2048  (bq|bk|bv contiguous)
    short* bkb   = bqb + 2048;                        // 512
    short* bvb   = bkb + 512;                         // 512
    short* bob   = bvb + 512;                         // 2048
    short* Wo_t  = bob + 2048;                        // 4,194,304
    short* Qf    = Wo_t + (long)4194304;              // 8,388,608
    short* KVf   = Qf + (long)8388608;                // 4,194,304
    short* Vtp   = KVf + (long)4194304;               // 2,097,152
    short* Attn  = Vtp + (long)2097152;               // 8,388,608  (~88.6 MB total)

    detect_k<<<1, 64, 0, stream>>>((const unsigned short*)x, flags);

    // merged conversions: x -> xb plus the 4 bias vectors
    convert_all_k<<<4099, 256, 0, stream>>>(x, xb, bq, bk, bv, bo,
                                            bqb, bkb, bvb, bob, flags);

    // all 4 weight transposes in one launch
    transpose4_k<<<dim3(20, 32), 256, 0, stream>>>(Wq, Wk, Wv, Wo,
                                                   Wq_t, Wkv_t, Wo_t, flags);

    // merged QKV projection: Bt = [Wq_t; Wk_t; Wv_t] (contiguous), bias =
    // [bq|bk|bv] (contiguous). cols 0..2047 -> Qf, 2048..3071 -> KVf.
    // 128x96 tile -> 32x32 = 1024 blocks = 4/CU.
    gemm_bt<96><<<1024, 256, 0, stream>>>(xb, Wq_t, bqb, 3072,
                                          Qf, KVf, 2048, nullptr, flags,
                                          4096, 3072, 2048, 32);

    transpose_k<<<dim3(2, 32, 2), 256, 0, stream>>>(KVf + 512, Vtp, 2048, 1024,
                                                    (long)2048 * 1024, (long)512 * 2048, flags + 1);

    attn_k<<<1024, 256, 0, stream>>>(Qf, KVf, Vtp, Attn);

    // output projection: 128x64 tile -> 32x32 = 1024 blocks = 4/CU.
    gemm_bt<64><<<1024, 256, 0, stream>>>(Attn, Wo_t, bob, 2048,
                                          (short*)d_out, nullptr, 0,
                                          (float*)d_out, flags,
                                          4096, 2048, 2048, 32);
}

// Round 9
// 400.547 us; speedup vs baseline: 1.1537x; 1.1537x over previous
//
#include <hip/hip_runtime.h>
#include <stdint.h>

typedef __attribute__((ext_vector_type(8))) short bf16x8;   // 8 bf16 in 4 VGPRs
typedef __attribute__((ext_vector_type(4))) float f32x4;

#define LOG2E 1.44269504088896f
#define T_SEQ 2048

__device__ __forceinline__ float bf2f(short s) {
    unsigned u = ((unsigned)(unsigned short)s) << 16;
    float f; __builtin_memcpy(&f, &u, 4); return f;
}
__device__ __forceinline__ short f2bf(float f) {
    unsigned u; __builtin_memcpy(&u, &f, 4);
    u = (u + 0x7FFFu + ((u >> 16) & 1u)) >> 16;   // RNE
    return (short)u;
}
__device__ __forceinline__ short f2bf_trunc(float f) {
    unsigned u; __builtin_memcpy(&u, &f, 4);
    return (short)(u >> 16);                      // truncate (bias cancels in P/l ratio)
}

#define GLDS(g, l) __builtin_amdgcn_global_load_lds( \
    (const __attribute__((address_space(1))) void*)(g), \
    (__attribute__((address_space(3))) void*)(l), 16, 0, 0)

// ---------------------------------------------------------------------------
// fp32-vs-bf16 input detection. flag[0]=1 if fp32.
__global__ void detect_k(const unsigned short* __restrict__ x, int* __restrict__ flag) {
    int lane = threadIdx.x;            // 64 threads
    int cnt = 0;
    for (int i = lane; i < 2048; i += 64) {
        int e = (x[i] >> 7) & 0xFF;
        if (e >= 0xC0) cnt++;
    }
    cnt += __shfl_xor(cnt, 1);
    cnt += __shfl_xor(cnt, 2);
    cnt += __shfl_xor(cnt, 4);
    cnt += __shfl_xor(cnt, 8);
    cnt += __shfl_xor(cnt, 16);
    cnt += __shfl_xor(cnt, 32);
    if (lane == 0) { flag[0] = (cnt >= 32) ? 1 : 0; flag[1] = 0; }
}

// ---------------------------------------------------------------------------
// merged x-conversion (blocks 0..4095) + 4 bias vectors (blocks 4096..4098:
// [bq:2048 | bk:512 | bv:512 | bo:2048])
__global__ __launch_bounds__(256) void convert_all_k(
    const void* __restrict__ x, short* __restrict__ xb,
    const void* __restrict__ b0, const void* __restrict__ b1,
    const void* __restrict__ b2, const void* __restrict__ b3,
    short* __restrict__ o0, short* __restrict__ o1,
    short* __restrict__ o2, short* __restrict__ o3,
    const int* __restrict__ flag)
{
    const int blk = blockIdx.x;
    const int fp32 = *flag;
    if (blk < 4096) {
        int i = (blk * 256 + threadIdx.x) * 8;
        bf16x8 v;
        if (fp32) {
            const float* f = (const float*)x + i;
            #pragma unroll
            for (int j = 0; j < 8; ++j) v[j] = f2bf(f[j]);
        } else {
            v = *(const bf16x8*)((const short*)x + i);
        }
        *(bf16x8*)(xb + i) = v;
        return;
    }
    int i = ((blk - 4096) * 256 + threadIdx.x) * 8;
    const void* in; short* out; int off;
    if      (i < 2048) { in = b0; out = o0; off = i; }
    else if (i < 2560) { in = b1; out = o1; off = i - 2048; }
    else if (i < 3072) { in = b2; out = o2; off = i - 2560; }
    else if (i < 5120) { in = b3; out = o3; off = i - 3072; }
    else return;
    bf16x8 v;
    if (fp32) {
        const float* f = (const float*)in + off;
        #pragma unroll
        for (int j = 0; j < 8; ++j) v[j] = f2bf(f[j]);
    } else {
        v = *(const bf16x8*)((const short*)in + off);
    }
    *(bf16x8*)(out + off) = v;
}

// ---------------------------------------------------------------------------
// out[c*R + r] = in[r*ldi + c]   (batched via blockIdx.z), input fp32 or bf16
// per flag, output bf16. grid: (C/256, R/64, batch), block 256.
__global__ __launch_bounds__(256) void transpose_k(
    const void* __restrict__ in_, short* __restrict__ out,
    int R, int ldi, long ibstride, long obstride, const int* __restrict__ flag)
{
    short* ob = out + (long)blockIdx.z * obstride;
    int c = blockIdx.x * 256 + threadIdx.x;
    int r0 = blockIdx.y * 64;
    int fp32 = *flag;
    if (fp32) {
        const float* ib = (const float*)in_ + (long)blockIdx.z * ibstride;
        for (int rr = 0; rr < 64; rr += 8) {
            bf16x8 v;
            #pragma unroll
            for (int j = 0; j < 8; ++j) v[j] = f2bf(ib[(long)(r0 + rr + j) * ldi + c]);
            *(bf16x8*)(ob + (long)c * R + r0 + rr) = v;
        }
    } else {
        const short* ib = (const short*)in_ + (long)blockIdx.z * ibstride;
        for (int rr = 0; rr < 64; rr += 8) {
            bf16x8 v;
            #pragma unroll
            for (int j = 0; j < 8; ++j) v[j] = ib[(long)(r0 + rr + j) * ldi + c];
            *(bf16x8*)(ob + (long)c * R + r0 + rr) = v;
        }
    }
}

// ---------------------------------------------------------------------------
// all 4 weight transposes in ONE launch. grid (20, 32):
//  bx 0-7: Wq->Wq_t | 8-9: Wk->Wkv_t | 10-11: Wv->Wkv_t+512*2048 | 12-19: Wo->Wo_t
// All are 2048-row inputs (R=2048).
__global__ __launch_bounds__(256) void transpose4_k(
    const void* __restrict__ Wq, const void* __restrict__ Wk,
    const void* __restrict__ Wv, const void* __restrict__ Wo,
    short* __restrict__ Wq_t, short* __restrict__ Wkv_t,
    short* __restrict__ Wo_t, const int* __restrict__ flag)
{
    const int bx = blockIdx.x;
    const void* in; short* out; int ldi, c;
    if (bx < 8)       { in = Wq; out = Wq_t;                     ldi = 2048; c = bx * 256 + threadIdx.x; }
    else if (bx < 10) { in = Wk; out = Wkv_t;                    ldi = 512;  c = (bx - 8) * 256 + threadIdx.x; }
    else if (bx < 12) { in = Wv; out = Wkv_t + (long)512 * 2048; ldi = 512;  c = (bx - 10) * 256 + threadIdx.x; }
    else              { in = Wo; out = Wo_t;                     ldi = 2048; c = (bx - 12) * 256 + threadIdx.x; }
    const int r0 = blockIdx.y * 64;
    const int fp32 = *flag;
    if (fp32) {
        const float* ib = (const float*)in;
        for (int rr = 0; rr < 64; rr += 8) {
            bf16x8 v;
            #pragma unroll
            for (int j = 0; j < 8; ++j) v[j] = f2bf(ib[(long)(r0 + rr + j) * ldi + c]);
            *(bf16x8*)(out + (long)c * 2048 + r0 + rr) = v;
        }
    } else {
        const short* ib = (const short*)in;
        for (int rr = 0; rr < 64; rr += 8) {
            bf16x8 v;
            #pragma unroll
            for (int j = 0; j < 8; ++j) v[j] = ib[(long)(r0 + rr + j) * ldi + c];
            *(bf16x8*)(out + (long)c * 2048 + r0 + rr) = v;
        }
    }
}

// ---------------------------------------------------------------------------
// gemm_bt: C = A[M,K] @ Bt[N,K]^T + bias. 128x128 tile, 4 waves.
// r9: BK=64 — r8 closed the TLP lever (BN=96: occupancy +9pt but dur +6%,
// FETCH +67%); back to BN=128 (r6 best) and attack the per-step fixed cost
// instead: MfmaUtil 19% says the GLDS->vmcnt(0)->barrier drain ~4x the 16
// MFMAs of compute per BK=32 step. BK=64 halves the barrier/drain count at
// the same total loads (8 GLDS + 32 MFMA per step). LDS 32 KB (cap 5/CU;
// grid keeps 3/CU).
// Staging derived from chunk index c (r7 lesson): row=c>>3, k-chunk
// (c&7)^(row&7) — XOR keeps ds_read_b128 at 2-way (free): for fixed
// quad/k-half, rows 0..15 spread across all 8 16B-slots.
// XCD-aware bijective block swizzle kept (r6: FETCH 78->60MB). nbx = blocks
// along N; requires gridDim.x % 8 == 0.
#define BK 64
__global__ __launch_bounds__(256, 3) void gemm_bt(
    const short* __restrict__ A, const short* __restrict__ Bt,
    const short* __restrict__ bias1, int nsplit,
    short* __restrict__ C, short* __restrict__ C2, int n2,
    float* __restrict__ Cf, const int* __restrict__ flag,
    int M, int N, int K, int nbx)
{
    __shared__ short a_lds[128 * BK];   // 16 KB
    __shared__ short b_lds[128 * BK];   // 16 KB
    const int tid = threadIdx.x;
    const int wave = tid >> 6, lane = tid & 63;
    const int quad = lane >> 4, l16 = lane & 15;

    // XCD-aware bijective swizzle: XCD (bid%8) gets contiguous chunk of work
    const int nwg = gridDim.x;
    const int swz = (blockIdx.x & 7) * (nwg >> 3) + (blockIdx.x >> 3);
    const int by = swz / nbx;
    const int bx = swz - by * nbx;
    const int m0 = by * 128, n0 = bx * 128;
    const int wm = (wave >> 1) * 64, wn = (wave & 1) * 64;

    // staging: 128x64 tile = 1024 16B-chunks; thread stages chunks
    // c = g*256+tid, g=0..3. row = c>>3, k-chunk = (c&7)^(row&7).
    long aoff[4], boff[4];
    #pragma unroll
    for (int g = 0; g < 4; ++g) {
        const int c = g * 256 + tid;
        const int row = c >> 3;
        const int kc = (c & 7) ^ (row & 7);
        aoff[g] = (long)(m0 + row) * K + kc * 8;
        boff[g] = (long)(n0 + row) * K + kc * 8;
    }

    // fragment read offsets: global (row, kchunk=h*4+quad) lives at LDS
    // slot row*8 + (kchunk ^ (row&7))  (shorts: *8)
    int aro[4][2], bro[4][2];
    #pragma unroll
    for (int t = 0; t < 4; ++t) {
        const int ra = wm + t * 16 + l16;
        const int rb = wn + t * 16 + l16;
        #pragma unroll
        for (int h = 0; h < 2; ++h) {
            aro[t][h] = ra * BK + (((h << 2) + quad) ^ (ra & 7)) * 8;
            bro[t][h] = rb * BK + (((h << 2) + quad) ^ (rb & 7)) * 8;
        }
    }

    f32x4 acc[4][4];
    #pragma unroll
    for (int i = 0; i < 4; ++i)
        #pragma unroll
        for (int j = 0; j < 4; ++j)
            acc[i][j] = (f32x4){0.f, 0.f, 0.f, 0.f};

    for (int k0 = 0; k0 < K; k0 += BK) {
        __syncthreads();
        #pragma unroll
        for (int g = 0; g < 4; ++g)
            GLDS(A + aoff[g] + k0, a_lds + (g * 256 + wave * 64) * 8);
        #pragma unroll
        for (int g = 0; g < 4; ++g)
            GLDS(Bt + boff[g] + k0, b_lds + (g * 256 + wave * 64) * 8);
        __syncthreads();
        #pragma unroll
        for (int h = 0; h < 2; ++h) {
            bf16x8 af[4], bfr[4];
            #pragma unroll
            for (int t = 0; t < 4; ++t) af[t] = *(const bf16x8*)(a_lds + aro[t][h]);
            #pragma unroll
            for (int t = 0; t < 4; ++t) bfr[t] = *(const bf16x8*)(b_lds + bro[t][h]);
            #pragma unroll
            for (int mt = 0; mt < 4; ++mt)
                #pragma unroll
                for (int nt = 0; nt < 4; ++nt)
                    acc[mt][nt] = __builtin_amdgcn_mfma_f32_16x16x32_bf16(
                        af[mt], bfr[nt], acc[mt][nt], 0, 0, 0);
        }
    }

    const int f32o = Cf ? *flag : 0;
    #pragma unroll
    for (int nt = 0; nt < 4; ++nt) {
        int col = n0 + wn + nt * 16 + l16;
        float bb = bf2f(bias1[col < nsplit ? col : 0]);
        #pragma unroll
        for (int mt = 0; mt < 4; ++mt)
            #pragma unroll
            for (int r = 0; r < 4; ++r) {
                int row = m0 + wm + mt * 16 + quad * 4 + r;
                float val = acc[mt][nt][r] + bb;
                if (f32o) {
                    Cf[(long)row * N + col] = val;
                } else if (C2) {
                    if (col < n2) C[(long)row * n2 + col] = f2bf(val);
                    else          C2[(long)row * (N - n2) + (col - n2)] = f2bf(val);
                } else {
                    C[(long)row * N + col] = f2bf(val);
                }
            }
    }
}

// ---------------------------------------------------------------------------
// Flash attention v7: NO split-KV, NO atomics. One block per (q-tile, bh) =
// 1024 blocks; each block walks all its keys (2..32 steps of 64), keeps O,l
// in registers, normalizes locally and writes bf16 Attn directly.
// Balance: QTMAP partitions qt into residue classes {w,w+4,w+8,w+12} each
// summing to 34 steps -> every CU ~68 steps. LDS 34816B, launch_bounds(256,4)
// -> 4 blocks/CU, grid fully resident.
#define PLD 68
__global__ __launch_bounds__(256, 4) void attn_k(
    const short* __restrict__ Qf, const short* __restrict__ KVf,
    const short* __restrict__ Vt, short* __restrict__ Attn)
{
    __shared__ short k_lds[64 * PLD];
    __shared__ short vt_lds[64 * PLD];
    __shared__ short p_lds[4 * 32 * PLD];
    const int tid = threadIdx.x;
    const int wave = tid >> 6, lane = tid & 63;
    const int quad = lane >> 4, l16 = lane & 15;

    // id -> (qt, bh). QTMAP: balanced residue-class partition (see header).
    const int id = blockIdx.x;
    const int bh = id & 63;
    const int w = id >> 6;                    // 0..15
    const int QTMAP[16] = {15,13,11,9, 0,2,4,6, 14,12,10,8, 1,3,5,7};
    const int qt = QTMAP[w];
    const int b = bh >> 5, h = bh & 31, hkv = h >> 2;
    const int q0 = qt * 128;
    const int nsteps = 2 * (qt + 1);          // keys [0, (qt+1)*128), 64/step

    // Q A-frags (2 m-tiles), fold exact 1/8 scale
    bf16x8 aq[2][2];
    #pragma unroll
    for (int mt = 0; mt < 2; ++mt) {
        const short* qp = Qf + ((long)(b * T_SEQ + q0 + wave * 32 + mt * 16 + l16) * 2048
                                + h * 64 + quad * 8);
        aq[mt][0] = *(const bf16x8*)qp;
        aq[mt][1] = *(const bf16x8*)(qp + 32);
        #pragma unroll
        for (int j = 0; j < 8; ++j) {
            aq[mt][0][j] = f2bf(bf2f(aq[mt][0][j]) * 0.125f);
            aq[mt][1][j] = f2bf(bf2f(aq[mt][1][j]) * 0.125f);
        }
    }

    // ones B-frag: B[n=l16][k]=1 iff n==0  -> MFMA computes row-sums of P
    bf16x8 onesf;
    {
        short o = (l16 == 0) ? (short)0x3F80 : (short)0;
        #pragma unroll
        for (int j = 0; j < 8; ++j) onesf[j] = o;
    }

    f32x4 o_acc[2][4];
    f32x4 l_acc[2];
    #pragma unroll
    for (int mt = 0; mt < 2; ++mt) {
        l_acc[mt] = (f32x4){0.f, 0.f, 0.f, 0.f};
        #pragma unroll
        for (int dt = 0; dt < 4; ++dt) o_acc[mt][dt] = (f32x4){0.f, 0.f, 0.f, 0.f};
    }

    // staging map: 512 16B-chunks per 64x64 tile, 2 per thread
    const int cA = tid, cB = 256 + tid;
    const int tA = cA >> 3, chA = cA & 7;
    const int tB = cB >> 3, chB = cB & 7;
    const short* kgA = KVf + ((long)(b * T_SEQ + tA) * 1024 + hkv * 64 + chA * 8);
    const short* kgB = KVf + ((long)(b * T_SEQ + tB) * 1024 + hkv * 64 + chB * 8);
    const short* vgA = Vt + ((long)((b * 8 + hkv) * 64 + tA) * 2048 + chA * 8);
    const short* vgB = Vt + ((long)((b * 8 + hkv) * 64 + tB) * 2048 + chB * 8);

    const int rowq0 = q0 + wave * 32 + quad * 4;     // mt adds 16
    short* pw = p_lds + (wave * 32 + quad * 4) * PLD + l16;
    const short* pr = p_lds + (wave * 32 + l16) * PLD + quad * 8;

    // prefetch step 0
    bf16x8 kA = *(const bf16x8*)(kgA);
    bf16x8 kB = *(const bf16x8*)(kgB);
    bf16x8 vA = *(const bf16x8*)(vgA);
    bf16x8 vB = *(const bf16x8*)(vgB);

    for (int s = 0; s < nsteps; ++s) {
        const int kt0 = s * 64;
        const int ktn = ((s + 1 < nsteps) ? (s + 1) : s) * 64;
        __syncthreads();   // prior step's frag reads done
        *(bf16x8*)(k_lds + tA * PLD + chA * 8) = kA;
        *(bf16x8*)(k_lds + tB * PLD + chB * 8) = kB;
        *(bf16x8*)(vt_lds + tA * PLD + chA * 8) = vA;
        *(bf16x8*)(vt_lds + tB * PLD + chB * 8) = vB;
        // issue next step's loads: full step of compute covers the latency
        kA = *(const bf16x8*)(kgA + (long)ktn * 1024);
        kB = *(const bf16x8*)(kgB + (long)ktn * 1024);
        vA = *(const bf16x8*)(vgA + ktn);
        vB = *(const bf16x8*)(vgB + ktn);
        __syncthreads();   // staging visible

        const int masked = (kt0 >= q0);
        // QK streamed per nt: S-tile -> exp -> P store
        #pragma unroll
        for (int nt = 0; nt < 4; ++nt) {
            bf16x8 bk0 = *(const bf16x8*)(k_lds + (nt * 16 + l16) * PLD + quad * 8);
            bf16x8 bk1 = *(const bf16x8*)(k_lds + (nt * 16 + l16) * PLD + 32 + quad * 8);
            #pragma unroll
            for (int mt = 0; mt < 2; ++mt) {
                f32x4 z = (f32x4){0.f, 0.f, 0.f, 0.f};
                z = __builtin_amdgcn_mfma_f32_16x16x32_bf16(aq[mt][0], bk0, z, 0, 0, 0);
                z = __builtin_amdgcn_mfma_f32_16x16x32_bf16(aq[mt][1], bk1, z, 0, 0, 0);
                if (!masked) {
                    #pragma unroll
                    for (int r = 0; r < 4; ++r)
                        z[r] = exp2f(fmaf(z[r], LOG2E, -16.0f));
                } else {
                    const int rowq = rowq0 + mt * 16;
                    const int tcol = kt0 + nt * 16 + l16;
                    #pragma unroll
                    for (int r = 0; r < 4; ++r) {
                        float e = exp2f(fmaf(z[r], LOG2E, -16.0f));
                        z[r] = (tcol <= rowq + r) ? e : 0.0f;
                    }
                }
                #pragma unroll
                for (int r = 0; r < 4; ++r)
                    pw[mt * 16 * PLD + r * PLD + nt * 16] = f2bf_trunc(z[r]);
            }
        }

        // PV: cache ap frags, dt-outer (bv read once per dt)
        bf16x8 ap[2][2];
        #pragma unroll
        for (int mt = 0; mt < 2; ++mt) {
            ap[mt][0] = *(const bf16x8*)(pr + mt * 16 * PLD);
            ap[mt][1] = *(const bf16x8*)(pr + mt * 16 * PLD + 32);
        }
        #pragma unroll
        for (int dt = 0; dt < 4; ++dt) {
            bf16x8 bv0 = *(const bf16x8*)(vt_lds + (dt * 16 + l16) * PLD + quad * 8);
            bf16x8 bv1 = *(const bf16x8*)(vt_lds + (dt * 16 + l16) * PLD + 32 + quad * 8);
            #pragma unroll
            for (int mt = 0; mt < 2; ++mt) {
                o_acc[mt][dt] = __builtin_amdgcn_mfma_f32_16x16x32_bf16(ap[mt][0], bv0, o_acc[mt][dt], 0, 0, 0);
                o_acc[mt][dt] = __builtin_amdgcn_mfma_f32_16x16x32_bf16(ap[mt][1], bv1, o_acc[mt][dt], 0, 0, 0);
            }
        }
        #pragma unroll
        for (int mt = 0; mt < 2; ++mt) {
            l_acc[mt] = __builtin_amdgcn_mfma_f32_16x16x32_bf16(ap[mt][0], onesf, l_acc[mt], 0, 0, 0);
            l_acc[mt] = __builtin_amdgcn_mfma_f32_16x16x32_bf16(ap[mt][1], onesf, l_acc[mt], 0, 0, 0);
        }
    }

    // epilogue: broadcast row-sum l (lives in lane quad*16, col 0), divide,
    // write bf16 Attn directly. Per row, dt loop covers 64 contiguous shorts.
    #pragma unroll
    for (int mt = 0; mt < 2; ++mt)
        #pragma unroll
        for (int r = 0; r < 4; ++r) {
            const float linv = 1.0f / __shfl(l_acc[mt][r], quad << 4);
            const int rowo = q0 + wave * 32 + mt * 16 + quad * 4 + r;
            short* ap = Attn + (long)(b * T_SEQ + rowo) * 2048 + h * 64 + l16;
            #pragma unroll
            for (int dt = 0; dt < 4; ++dt)
                ap[dt * 16] = f2bf(o_acc[mt][dt][r] * linv);
        }
}

// ---------------------------------------------------------------------------
extern "C" void kernel_launch(void* const* d_in, const int* in_sizes, int n_in,
                              void* d_out, int out_size, void* d_ws, size_t ws_size,
                              hipStream_t stream) {
    const void* x  = d_in[0];
    // d_in[1] = causal mask: applied analytically, unused
    const void* Wq = d_in[2];
    const void* bq = d_in[3];
    const void* Wk = d_in[4];
    const void* bk = d_in[5];
    const void* Wv = d_in[6];
    const void* bv = d_in[7];
    const void* Wo = d_in[8];
    const void* bo = d_in[9];

    short* ws    = (short*)d_ws;
    int*   flags = (int*)ws;                          // flags[0]=fp32?, flags[1]=0
    short* base  = ws + 16;
    short* xb    = base;                              // 4096*2048 = 8,388,608 sh
    short* Wq_t  = xb + (long)8388608;                // 2048*2048 = 4,194,304 sh
    short* Wkv_t = Wq_t + (long)4194304;              // 1024*2048 = 2,097,152 sh
    short* regB  = base + (long)17039360;             // past region A
    short* bqb   = regB;                              // 2048  (bq|bk|bv contiguous)
    short* bkb   = bqb + 2048;                        // 512
    short* bvb   = bkb + 512;                         // 512
    short* bob   = bvb + 512;                         // 2048
    short* Wo_t  = bob + 2048;                        // 4,194,304
    short* Qf    = Wo_t + (long)4194304;              // 8,388,608
    short* KVf   = Qf + (long)8388608;                // 4,194,304
    short* Vtp   = KVf + (long)4194304;               // 2,097,152
    short* Attn  = Vtp + (long)2097152;               // 8,388,608  (~88.6 MB total)

    detect_k<<<1, 64, 0, stream>>>((const unsigned short*)x, flags);

    // merged conversions: x -> xb plus the 4 bias vectors
    convert_all_k<<<4099, 256, 0, stream>>>(x, xb, bq, bk, bv, bo,
                                            bqb, bkb, bvb, bob, flags);

    // all 4 weight transposes in one launch
    transpose4_k<<<dim3(20, 32), 256, 0, stream>>>(Wq, Wk, Wv, Wo,
                                                   Wq_t, Wkv_t, Wo_t, flags);

    // merged QKV projection: Bt = [Wq_t; Wk_t; Wv_t] (contiguous), bias =
    // [bq|bk|bv] (contiguous). cols 0..2047 -> Qf, 2048..3071 -> KVf.
    // r6 geometry: 768 blocks (3/CU), nbx=24, XCD-swizzled; BK=64.
    gemm_bt<<<768, 256, 0, stream>>>(xb, Wq_t, bqb, 3072,
                                     Qf, KVf, 2048, nullptr, flags,
                                     4096, 3072, 2048, 24);

    transpose_k<<<dim3(2, 32, 2), 256, 0, stream>>>(KVf + 512, Vtp, 2048, 1024,
                                                    (long)2048 * 1024, (long)512 * 2048, flags + 1);

    attn_k<<<1024, 256, 0, stream>>>(Qf, KVf, Vtp, Attn);

    // output projection: r6 geometry: 512 blocks (2/CU), nbx=16; BK=64.
    gemm_bt<<<512, 256, 0, stream>>>(Attn, Wo_t, bob, 2048,
                                     (short*)d_out, nullptr, 0,
                                     (float*)d_out, flags,
                                     4096, 2048, 2048, 16);
}